// Round 10
// baseline (100.364 us; speedup 1.0000x reference)
//
#include <hip/hip_runtime.h>
#include <hip/hip_bf16.h>

typedef float f32x4 __attribute__((ext_vector_type(4)));
typedef float f32x16 __attribute__((ext_vector_type(16)));
typedef short bf16x8 __attribute__((ext_vector_type(8)));

#define MFMA16(A,B,C) __builtin_amdgcn_mfma_f32_16x16x32_bf16(A,B,C,0,0,0)
#define MFMA32(A,B,C) __builtin_amdgcn_mfma_f32_32x32x16_bf16(A,B,C,0,0,0)

__device__ __forceinline__ unsigned short f2bf(float f) {
    union { float f; unsigned u; } x; x.f = f;
    return (unsigned short)((x.u + 0x7FFFu + ((x.u >> 16) & 1u)) >> 16);
}

__device__ __forceinline__ float bf2f(unsigned short u) {
    union { unsigned u; float f; } x; x.u = ((unsigned)u) << 16; return x.f;
}

__device__ __forceinline__ unsigned fbits(float f) {
    union { float f; unsigned u; } x; x.f = f; return x.u;
}

__device__ __forceinline__ f32x16 zero16() {
    f32x16 z;
#pragma unroll
    for (int i = 0; i < 16; ++i) z[i] = 0.f;
    return z;
}

typedef const __attribute__((address_space(1))) unsigned int* as1_t;
typedef __attribute__((address_space(3))) unsigned int* as3_t;
__device__ __forceinline__ void gl_lds16(const unsigned short* g, unsigned short* l) {
    __builtin_amdgcn_global_load_lds((as1_t)g, (as3_t)l, 16, 0, 0);
}

// ---------------- Kernel 1a: WT[n][k] = W_cat[k][n] bf16, coalesced reads -------
__global__ void prep_wt(const float* __restrict__ Wq, const float* __restrict__ Wk,
                        const float* __restrict__ Wv, unsigned short* __restrict__ WT) {
    int w = blockIdx.x % 3;
    int kt = blockIdx.x / 3;       // 0..31
    const float* src = (w == 0) ? Wq : (w == 1) ? Wk : Wv;
    int k0 = kt * 32;
#pragma unroll
    for (int j = 0; j < 16; ++j) {
        int idx = threadIdx.x + j * 256;       // 0..4095
        int r = idx >> 7, c = idx & 127;
        float v = src[(size_t)(k0 + r) * 128 + c];
        WT[(size_t)(w * 128 + c) * 1024 + k0 + r] = f2bf(v);
    }
}

// ---------------- Kernel 1b: Xb = bf16(X) ---------------------------------------
__global__ __launch_bounds__(256) void prep_x(const float* __restrict__ X,
                                              unsigned short* __restrict__ Xb) {
    int i = blockIdx.x * 256 + threadIdx.x;
#pragma unroll
    for (int r = 0; r < 8; ++r) {
        int idx = i + r * 262144;
        float4 x = ((const float4*)X)[idx];
        ushort4 p;
        p.x = f2bf(x.x); p.y = f2bf(x.y); p.z = f2bf(x.z); p.w = f2bf(x.w);
        ((ushort4*)Xb)[idx] = p;
    }
}

// ---------------- Kernel 2: QKV projection, LDS-staged GEMM ---------------------
// BM=64 (grid 128,4 = 512 blocks). V keys stored permuted:
// storage pos = (s & ~15) | swap23(s & 15), so attn PV B-frags are single b128.
__global__ __launch_bounds__(256) void proj(const unsigned short* __restrict__ Xb,
        const unsigned short* __restrict__ WT, unsigned short* __restrict__ Qc,
        unsigned short* __restrict__ Kc, unsigned short* __restrict__ VT) {
    int tid = threadIdx.x;
    int w = tid >> 6, lane = tid & 63;
    int lr = lane & 15, lg = lane >> 4;
    int wr = w >> 1, wc = w & 1;              // 2x2 wave grid
    int m0 = blockIdx.x * 64;
    int n0 = blockIdx.y * 96;

    __shared__ __align__(16) unsigned short Ab[2][64 * 64];   // 8KB x2
    __shared__ __align__(16) unsigned short Bb[2][96 * 64];   // 12KB x2

    f32x4 acc[2][3];
#pragma unroll
    for (int i = 0; i < 2; ++i)
#pragma unroll
        for (int j = 0; j < 3; ++j) acc[i][j] = f32x4{0.f,0.f,0.f,0.f};

    int srow = lane >> 3;
    int sunit = lane & 7;
    const unsigned short* aSrc = Xb + (size_t)(m0 + srow) * 1024 + sunit * 8;
    const unsigned short* bSrc = WT + (size_t)(n0 + srow) * 1024 + sunit * 8;

    auto STAGE = [&](int bsel, int st) {
        int kk = st * 64;
#pragma unroll
        for (int i = 0; i < 2; ++i) {
            int blk = w * 2 + i;              // 0..7
            gl_lds16(aSrc + (size_t)blk * 8 * 1024 + kk, &Ab[bsel][blk * 512]);
        }
#pragma unroll
        for (int i = 0; i < 3; ++i) {
            int blk = w * 3 + i;              // 0..11
            gl_lds16(bSrc + (size_t)blk * 8 * 1024 + kk, &Bb[bsel][blk * 512]);
        }
    };

    STAGE(0, 0);
    __syncthreads();

    for (int st = 0; st < 16; ++st) {
        int cur = st & 1;
        if (st + 1 < 16) STAGE(cur ^ 1, st + 1);

        const unsigned short* ab = &Ab[cur][0];
        const unsigned short* bb = &Bb[cur][0];
#pragma unroll
        for (int ksub = 0; ksub < 2; ++ksub) {
            int ko = ksub * 32 + lg * 8;
            bf16x8 af[2], bf[3];
#pragma unroll
            for (int mt = 0; mt < 2; ++mt)
                af[mt] = *(const bf16x8*)(ab + (wr * 32 + mt * 16 + lr) * 64 + ko);
#pragma unroll
            for (int nt = 0; nt < 3; ++nt)
                bf[nt] = *(const bf16x8*)(bb + (wc * 48 + nt * 16 + lr) * 64 + ko);
#pragma unroll
            for (int mt = 0; mt < 2; ++mt)
#pragma unroll
                for (int nt = 0; nt < 3; ++nt)
                    acc[mt][nt] = MFMA16(af[mt], bf[nt], acc[mt][nt]);
        }
        __syncthreads();
    }

    int b = m0 >> 12;
    int sbase = (m0 & 4095) + wr * 32;
#pragma unroll
    for (int nt = 0; nt < 3; ++nt) {
        int gcol = n0 + wc * 48 + nt * 16 + lr;     // 0..383
        int tensor = gcol >> 7;                     // 0=Q 1=K 2=V
#pragma unroll
        for (int mt = 0; mt < 2; ++mt) {
            int sloc = sbase + mt * 16 + 4 * lg;
            if (tensor == 2) {
                int vcol = gcol & 127;
                // key-permuted storage: 4-key group lg -> group swap(lg bits)
                int slocV = (sloc & ~15) | (((lg & 1) << 3) | ((lg >> 1) << 2));
                ushort4 pk;
                pk.x = f2bf(acc[mt][nt][0]); pk.y = f2bf(acc[mt][nt][1]);
                pk.z = f2bf(acc[mt][nt][2]); pk.w = f2bf(acc[mt][nt][3]);
                *(ushort4*)(VT + (size_t)(b * 128 + vcol) * 4096 + slocV) = pk;
            } else {
                int within = gcol & 127;
                int comp = within >> 6;
                int col64 = within & 63;
                float sc = (tensor == 0) ? 0.1803368801f : 1.0f;  // (1/8)*log2e in Q
                unsigned short* dst = (tensor == 0) ? Qc : Kc;
                size_t rowb = (size_t)(comp * 2 + b) * 4096 + sloc;
#pragma unroll
                for (int r = 0; r < 4; ++r)
                    dst[(rowb + r) * 64 + col64] = f2bf(acc[mt][nt][r] * sc);
            }
        }
    }
}

// ---------------- Kernel 3: flash attention, 64 unique q per wave ---------------
// Block = 4 waves x 64q = 256q, full 128v per wave. K/V frags read from LDS once
// per iter and reused across the wave's two 32-q groups IN REGISTERS (no S
// duplication, no P exchange). 8 k-splits of 512 keys; bf16 partials.
__global__ __launch_bounds__(256, 2) void attn(const unsigned short* __restrict__ Qc,
        const unsigned short* __restrict__ Kc, const unsigned short* __restrict__ VT,
        unsigned short* __restrict__ Opart, float* __restrict__ Lpart) {
    int tid = threadIdx.x;
    int wave = tid >> 6, lane = tid & 63;
    int l31 = lane & 31, hi = lane >> 5;
    int x7 = l31 & 7;
    int b = blockIdx.y;
    int comp = blockIdx.z >> 3, split = blockIdx.z & 7;
    int q0 = blockIdx.x * 256 + wave * 64;
    int kstart = split * 512;

    __shared__ __align__(16) unsigned short kbuf[2][64 * 64];   // 8KB x2
    __shared__ __align__(16) unsigned short vbuf[2][128 * 64];  // 16KB x2

    // Q B-frags for two 32-q groups: lane holds col q = q0 + g*32 + l31
    const unsigned short* Qbase = Qc + ((size_t)(comp * 2 + b) * 4096 + q0 + l31) * 64 + hi * 8;
    bf16x8 qB[2][4];
#pragma unroll
    for (int g = 0; g < 2; ++g)
#pragma unroll
        for (int j = 0; j < 4; ++j)
            qB[g][j] = *(const bf16x8*)(Qbase + g * 32 * 64 + j * 16);

    f32x16 o[2][4];
#pragma unroll
    for (int g = 0; g < 2; ++g)
#pragma unroll
        for (int vt = 0; vt < 4; ++vt) o[g][vt] = zero16();
    float lsum0 = 0.f, lsum1 = 0.f;

    const unsigned short* kSrc = Kc + ((size_t)(comp * 2 + b) * 4096 + kstart
                                       + wave * 8 + (lane >> 3)) * 64
                                    + ((lane & 7) ^ (lane >> 3)) * 8;
    const unsigned short* vSrc = VT + ((size_t)b * 128 + (tid >> 3)) * 4096
                                    + kstart + ((lane & 7) ^ (lane >> 3)) * 8;

    auto STAGE = [&](int bsel, int it) {
        const unsigned short* ks = kSrc + (size_t)it * 4096;
        gl_lds16(ks,        &kbuf[bsel][wave * 512]);
        gl_lds16(ks + 2048, &kbuf[bsel][2048 + wave * 512]);
        const unsigned short* vs = vSrc + it * 64;
#pragma unroll
        for (int ri = 0; ri < 4; ++ri)
            gl_lds16(vs + (size_t)ri * 32 * 4096, &vbuf[bsel][ri * 2048 + wave * 512]);
    };

    STAGE(0, 0);
    __syncthreads();

    for (int it = 0; it < 8; ++it) {
        int cur = it & 1;
        if (it + 1 < 8) STAGE(cur ^ 1, it + 1);

        const unsigned short* kb = &kbuf[cur][0];
        const unsigned short* vb = &vbuf[cur][0];

        // S^T for both q-groups; K A-frags read once from LDS, reused in regs
        f32x16 st00 = zero16(), st01 = zero16(), st10 = zero16(), st11 = zero16();
        __builtin_amdgcn_s_setprio(1);
#pragma unroll
        for (int j = 0; j < 4; ++j) {
            int ku = ((j * 2 + hi) ^ x7) * 8;
            bf16x8 kA0 = *(const bf16x8*)(kb + l31 * 64 + ku);
            bf16x8 kA1 = *(const bf16x8*)(kb + (32 + l31) * 64 + ku);
            st00 = MFMA32(kA0, qB[0][j], st00);
            st01 = MFMA32(kA1, qB[0][j], st01);
            st10 = MFMA32(kA0, qB[1][j], st10);
            st11 = MFMA32(kA1, qB[1][j], st11);
        }
        __builtin_amdgcn_s_setprio(0);

        // exp2 + in-register pack (v_perm truncation) + VALU row-sum partials
        union W4 { unsigned u[4]; bf16x8 v; };
        W4 wP[2][4];
#pragma unroll
        for (int i2 = 0; i2 < 4; ++i2) {
            float a0 = __builtin_amdgcn_exp2f(st00[2 * i2]);
            float a1 = __builtin_amdgcn_exp2f(st00[2 * i2 + 1]);
            float a2 = __builtin_amdgcn_exp2f(st00[8 + 2 * i2]);
            float a3 = __builtin_amdgcn_exp2f(st00[9 + 2 * i2]);
            float b0 = __builtin_amdgcn_exp2f(st01[2 * i2]);
            float b1 = __builtin_amdgcn_exp2f(st01[2 * i2 + 1]);
            float b2 = __builtin_amdgcn_exp2f(st01[8 + 2 * i2]);
            float b3 = __builtin_amdgcn_exp2f(st01[9 + 2 * i2]);
            lsum0 += (a0 + a1) + (a2 + a3) + (b0 + b1) + (b2 + b3);
            wP[0][0].u[i2] = __builtin_amdgcn_perm(fbits(a1), fbits(a0), 0x07060302);
            wP[0][1].u[i2] = __builtin_amdgcn_perm(fbits(a3), fbits(a2), 0x07060302);
            wP[0][2].u[i2] = __builtin_amdgcn_perm(fbits(b1), fbits(b0), 0x07060302);
            wP[0][3].u[i2] = __builtin_amdgcn_perm(fbits(b3), fbits(b2), 0x07060302);
        }
#pragma unroll
        for (int i2 = 0; i2 < 4; ++i2) {
            float a0 = __builtin_amdgcn_exp2f(st10[2 * i2]);
            float a1 = __builtin_amdgcn_exp2f(st10[2 * i2 + 1]);
            float a2 = __builtin_amdgcn_exp2f(st10[8 + 2 * i2]);
            float a3 = __builtin_amdgcn_exp2f(st10[9 + 2 * i2]);
            float b0 = __builtin_amdgcn_exp2f(st11[2 * i2]);
            float b1 = __builtin_amdgcn_exp2f(st11[2 * i2 + 1]);
            float b2 = __builtin_amdgcn_exp2f(st11[8 + 2 * i2]);
            float b3 = __builtin_amdgcn_exp2f(st11[9 + 2 * i2]);
            lsum1 += (a0 + a1) + (a2 + a3) + (b0 + b1) + (b2 + b3);
            wP[1][0].u[i2] = __builtin_amdgcn_perm(fbits(a1), fbits(a0), 0x07060302);
            wP[1][1].u[i2] = __builtin_amdgcn_perm(fbits(a3), fbits(a2), 0x07060302);
            wP[1][2].u[i2] = __builtin_amdgcn_perm(fbits(b1), fbits(b0), 0x07060302);
            wP[1][3].u[i2] = __builtin_amdgcn_perm(fbits(b3), fbits(b2), 0x07060302);
        }

        // PV: V B-frags read once (16 b128), each used by both q-groups
        __builtin_amdgcn_s_setprio(1);
#pragma unroll
        for (int vt = 0; vt < 4; ++vt) {
            const unsigned short* vrow = vb + (vt * 32 + l31) * 64;
            bf16x8 v0 = *(const bf16x8*)(vrow + ((0 + hi) ^ x7) * 8);
            bf16x8 v1 = *(const bf16x8*)(vrow + ((2 + hi) ^ x7) * 8);
            bf16x8 v2 = *(const bf16x8*)(vrow + ((4 + hi) ^ x7) * 8);
            bf16x8 v3 = *(const bf16x8*)(vrow + ((6 + hi) ^ x7) * 8);
#pragma unroll
            for (int g = 0; g < 2; ++g) {
                o[g][vt] = MFMA32(wP[g][0].v, v0, o[g][vt]);
                o[g][vt] = MFMA32(wP[g][1].v, v1, o[g][vt]);
                o[g][vt] = MFMA32(wP[g][2].v, v2, o[g][vt]);
                o[g][vt] = MFMA32(wP[g][3].v, v3, o[g][vt]);
            }
        }
        __builtin_amdgcn_s_setprio(0);
        __syncthreads();
    }

    int base = (b * 2 + comp) * 8 + split;
    unsigned short* op = Opart + (size_t)base * 4096 * 128;
#pragma unroll
    for (int g = 0; g < 2; ++g)
#pragma unroll
        for (int vt = 0; vt < 4; ++vt)
#pragma unroll
            for (int r = 0; r < 16; ++r) {
                int qr = (r & 3) + 8 * (r >> 2) + 4 * hi;
                op[(size_t)(q0 + g * 32 + qr) * 128 + vt * 32 + l31] = f2bf(o[g][vt][r]);
            }
    float ls0 = lsum0 + __shfl_xor(lsum0, 32, 64);
    float ls1 = lsum1 + __shfl_xor(lsum1, 32, 64);
    if (hi == 0) {
        float* lp = Lpart + (size_t)base * 4096 + q0;
        lp[l31] = ls0;
        lp[32 + l31] = ls1;
    }
}

// ---------------- Kernel 4: out = (SUM O1s)/l1 - lam * (SUM O2s)/l2 --------------
__global__ __launch_bounds__(256) void combine(const unsigned short* __restrict__ Opart,
        const float* __restrict__ Lpart, const float* __restrict__ lamp,
        float* __restrict__ out) {
    float lam = lamp[0];
    int i = blockIdx.x * 256 + threadIdx.x;   // float4 units over 2*4096*32
    int row = i >> 5;
    int c4  = i & 31;
    int b = row >> 12, q = row & 4095;

    float l1 = 0.f, l2 = 0.f;
#pragma unroll
    for (int s = 0; s < 8; ++s) {
        l1 += Lpart[((size_t)((b * 2 + 0) * 8 + s)) * 4096 + q];
        l2 += Lpart[((size_t)((b * 2 + 1) * 8 + s)) * 4096 + q];
    }
    float rl1 = 1.0f / l1, rl2 = 1.0f / l2;

    size_t qoff = (size_t)q * 128 + c4 * 4;
    float a0 = 0.f, a1 = 0.f, a2 = 0.f, a3 = 0.f;
    float c0 = 0.f, c1 = 0.f, c2 = 0.f, c3 = 0.f;
#pragma unroll
    for (int s = 0; s < 8; ++s) {
        ushort4 p1 = *(const ushort4*)(Opart + (size_t)((b * 2 + 0) * 8 + s) * 4096 * 128 + qoff);
        ushort4 p2 = *(const ushort4*)(Opart + (size_t)((b * 2 + 1) * 8 + s) * 4096 * 128 + qoff);
        a0 += bf2f(p1.x); a1 += bf2f(p1.y); a2 += bf2f(p1.z); a3 += bf2f(p1.w);
        c0 += bf2f(p2.x); c1 += bf2f(p2.y); c2 += bf2f(p2.z); c3 += bf2f(p2.w);
    }
    float4 r;
    r.x = a0 * rl1 - lam * c0 * rl2;
    r.y = a1 * rl1 - lam * c1 * rl2;
    r.z = a2 * rl1 - lam * c2 * rl2;
    r.w = a3 * rl1 - lam * c3 * rl2;
    ((float4*)out)[i] = r;
}

extern "C" void kernel_launch(void* const* d_in, const int* in_sizes, int n_in,
                              void* d_out, int out_size, void* d_ws, size_t ws_size,
                              hipStream_t stream) {
    const float* X   = (const float*)d_in[0];
    const float* Wq  = (const float*)d_in[1];
    const float* Wk  = (const float*)d_in[2];
    const float* Wv  = (const float*)d_in[3];
    const float* lam = (const float*)d_in[4];
    float* out = (float*)d_out;

    char* ws = (char*)d_ws;
    // Layout (Opart aliases WT+Xb: proj finishes before attn writes, same stream)
    unsigned short* Qc = (unsigned short*)(ws);                    // [2][2][4096][64]  2MB
    unsigned short* Kc = (unsigned short*)(ws + 2097152);          // [2][2][4096][64]  2MB
    unsigned short* VT = (unsigned short*)(ws + 4194304);          // [2][128][4096]    2MB
    unsigned short* WT = (unsigned short*)(ws + 6291456);          // 384x1024 bf16     768KB
    unsigned short* Xb = (unsigned short*)(ws + 7077888);          // 8192x1024 bf16    16MB
    unsigned short* Opart = (unsigned short*)(ws + 6291456);       // [32][4096][128] bf16 32MB (alias)
    float* Lpart = (float*)(ws + 39845888);                        // [32][4096] f32 512KB
    // end: 40,370,176 bytes

    prep_wt<<<dim3(96), dim3(256), 0, stream>>>(Wq, Wk, Wv, WT);
    prep_x<<<dim3(1024), dim3(256), 0, stream>>>(X, Xb);
    proj<<<dim3(128, 4), dim3(256), 0, stream>>>(Xb, WT, Qc, Kc, VT);
    attn<<<dim3(16, 2, 16), dim3(256), 0, stream>>>(Qc, Kc, VT, Opart, Lpart);
    combine<<<dim3(1024), dim3(256), 0, stream>>>(Opart, Lpart, lam, out);
}

// Round 11
// 75.326 us; speedup vs baseline: 1.3324x; 1.3324x over previous
//
#include <hip/hip_runtime.h>
#include <hip/hip_bf16.h>

typedef float f32x4 __attribute__((ext_vector_type(4)));
typedef float f32x16 __attribute__((ext_vector_type(16)));
typedef short bf16x8 __attribute__((ext_vector_type(8)));

#define MFMA16(A,B,C) __builtin_amdgcn_mfma_f32_16x16x32_bf16(A,B,C,0,0,0)
#define MFMA32(A,B,C) __builtin_amdgcn_mfma_f32_32x32x16_bf16(A,B,C,0,0,0)

__device__ __forceinline__ unsigned short f2bf(float f) {
    union { float f; unsigned u; } x; x.f = f;
    return (unsigned short)((x.u + 0x7FFFu + ((x.u >> 16) & 1u)) >> 16);
}

__device__ __forceinline__ float bf2f(unsigned short u) {
    union { unsigned u; float f; } x; x.u = ((unsigned)u) << 16; return x.f;
}

__device__ __forceinline__ unsigned fbits(float f) {
    union { float f; unsigned u; } x; x.f = f; return x.u;
}

__device__ __forceinline__ f32x16 zero16() {
    f32x16 z;
#pragma unroll
    for (int i = 0; i < 16; ++i) z[i] = 0.f;
    return z;
}

typedef const __attribute__((address_space(1))) unsigned int* as1_t;
typedef __attribute__((address_space(3))) unsigned int* as3_t;
__device__ __forceinline__ void gl_lds16(const unsigned short* g, unsigned short* l) {
    __builtin_amdgcn_global_load_lds((as1_t)g, (as3_t)l, 16, 0, 0);
}

// ---------------- Kernel 1a: WT[n][k] = W_cat[k][n] bf16, coalesced reads -------
__global__ void prep_wt(const float* __restrict__ Wq, const float* __restrict__ Wk,
                        const float* __restrict__ Wv, unsigned short* __restrict__ WT) {
    int w = blockIdx.x % 3;
    int kt = blockIdx.x / 3;       // 0..31
    const float* src = (w == 0) ? Wq : (w == 1) ? Wk : Wv;
    int k0 = kt * 32;
#pragma unroll
    for (int j = 0; j < 16; ++j) {
        int idx = threadIdx.x + j * 256;       // 0..4095
        int r = idx >> 7, c = idx & 127;
        float v = src[(size_t)(k0 + r) * 128 + c];
        WT[(size_t)(w * 128 + c) * 1024 + k0 + r] = f2bf(v);
    }
}

// ---------------- Kernel 1b: Xb = bf16(X) ---------------------------------------
__global__ __launch_bounds__(256) void prep_x(const float* __restrict__ X,
                                              unsigned short* __restrict__ Xb) {
    int i = blockIdx.x * 256 + threadIdx.x;
#pragma unroll
    for (int r = 0; r < 8; ++r) {
        int idx = i + r * 262144;
        float4 x = ((const float4*)X)[idx];
        ushort4 p;
        p.x = f2bf(x.x); p.y = f2bf(x.y); p.z = f2bf(x.z); p.w = f2bf(x.w);
        ((ushort4*)Xb)[idx] = p;
    }
}

// ---------------- Kernel 2: QKV projection, 3-buffer counted-vmcnt pipeline -----
// BM=64 (grid 128,4 = 512 blocks). V keys stored permuted:
// storage pos = (s & ~15) | swap23(s & 15), so attn PV B-frags are single b128.
__global__ __launch_bounds__(256) void proj(const unsigned short* __restrict__ Xb,
        const unsigned short* __restrict__ WT, unsigned short* __restrict__ Qc,
        unsigned short* __restrict__ Kc, unsigned short* __restrict__ VT) {
    int tid = threadIdx.x;
    int w = tid >> 6, lane = tid & 63;
    int lr = lane & 15, lg = lane >> 4;
    int wr = w >> 1, wc = w & 1;              // 2x2 wave grid
    int m0 = blockIdx.x * 64;
    int n0 = blockIdx.y * 96;

    __shared__ __align__(16) unsigned short Ab[3][64 * 64];   // 8KB x3
    __shared__ __align__(16) unsigned short Bb[3][96 * 64];   // 12KB x3

    f32x4 acc[2][3];
#pragma unroll
    for (int i = 0; i < 2; ++i)
#pragma unroll
        for (int j = 0; j < 3; ++j) acc[i][j] = f32x4{0.f,0.f,0.f,0.f};

    int srow = lane >> 3;
    int sunit = lane & 7;
    const unsigned short* aSrc = Xb + (size_t)(m0 + srow) * 1024 + sunit * 8;
    const unsigned short* bSrc = WT + (size_t)(n0 + srow) * 1024 + sunit * 8;

    auto STAGE = [&](unsigned short* ad, unsigned short* bd, int st) {
        int kk = st * 64;
#pragma unroll
        for (int i = 0; i < 2; ++i) {
            int blk = w * 2 + i;              // 0..7
            gl_lds16(aSrc + (size_t)blk * 8 * 1024 + kk, ad + blk * 512);
        }
#pragma unroll
        for (int i = 0; i < 3; ++i) {
            int blk = w * 3 + i;              // 0..11
            gl_lds16(bSrc + (size_t)blk * 8 * 1024 + kk, bd + blk * 512);
        }
    };

    unsigned short *a0 = Ab[0], *a1 = Ab[1], *a2 = Ab[2];
    unsigned short *b0 = Bb[0], *b1 = Bb[1], *b2 = Bb[2];
    STAGE(a0, b0, 0);
    STAGE(a1, b1, 1);

    for (int st = 0; st < 16; ++st) {
        // wait only for tile st (next tile's 5 loads stay in flight)
        if (st < 15) asm volatile("s_waitcnt vmcnt(5)" ::: "memory");
        else         asm volatile("s_waitcnt vmcnt(0)" ::: "memory");
        __builtin_amdgcn_sched_barrier(0);
        __builtin_amdgcn_s_barrier();
        __builtin_amdgcn_sched_barrier(0);
        if (st + 2 < 16) STAGE(a2, b2, st + 2);

        const unsigned short* ab = a0;
        const unsigned short* bb = b0;
#pragma unroll
        for (int ksub = 0; ksub < 2; ++ksub) {
            int ko = ksub * 32 + lg * 8;
            bf16x8 af[2], bf[3];
#pragma unroll
            for (int mt = 0; mt < 2; ++mt)
                af[mt] = *(const bf16x8*)(ab + (wr * 32 + mt * 16 + lr) * 64 + ko);
#pragma unroll
            for (int nt = 0; nt < 3; ++nt)
                bf[nt] = *(const bf16x8*)(bb + (wc * 48 + nt * 16 + lr) * 64 + ko);
#pragma unroll
            for (int mt = 0; mt < 2; ++mt)
#pragma unroll
                for (int nt = 0; nt < 3; ++nt)
                    acc[mt][nt] = MFMA16(af[mt], bf[nt], acc[mt][nt]);
        }
        // rotate buffers
        unsigned short* t;
        t = a0; a0 = a1; a1 = a2; a2 = t;
        t = b0; b0 = b1; b1 = b2; b2 = t;
    }

    int b = m0 >> 12;
    int sbase = (m0 & 4095) + wr * 32;
#pragma unroll
    for (int nt = 0; nt < 3; ++nt) {
        int gcol = n0 + wc * 48 + nt * 16 + lr;     // 0..383
        int tensor = gcol >> 7;                     // 0=Q 1=K 2=V
#pragma unroll
        for (int mt = 0; mt < 2; ++mt) {
            int sloc = sbase + mt * 16 + 4 * lg;
            if (tensor == 2) {
                int vcol = gcol & 127;
                // key-permuted storage: 4-key group lg -> group swap(lg bits)
                int slocV = (sloc & ~15) | (((lg & 1) << 3) | ((lg >> 1) << 2));
                ushort4 pk;
                pk.x = f2bf(acc[mt][nt][0]); pk.y = f2bf(acc[mt][nt][1]);
                pk.z = f2bf(acc[mt][nt][2]); pk.w = f2bf(acc[mt][nt][3]);
                *(ushort4*)(VT + (size_t)(b * 128 + vcol) * 4096 + slocV) = pk;
            } else {
                int within = gcol & 127;
                int comp = within >> 6;
                int col64 = within & 63;
                float sc = (tensor == 0) ? 0.1803368801f : 1.0f;  // (1/8)*log2e in Q
                unsigned short* dst = (tensor == 0) ? Qc : Kc;
                size_t rowb = (size_t)(comp * 2 + b) * 4096 + sloc;
#pragma unroll
                for (int r = 0; r < 4; ++r)
                    dst[(rowb + r) * 64 + col64] = f2bf(acc[mt][nt][r] * sc);
            }
        }
    }
}

// ---------------- Kernel 3: flash attention, R8 structure + 3-buffer pipeline ---
// 32q/wave x 128v, swapped QK^T, in-register softmax (v_perm pack), ones-MFMA
// row-sums, key-permuted V (bank-conflict-free b128 PV reads). bf16 partials.
__global__ __launch_bounds__(256, 2) void attn(const unsigned short* __restrict__ Qc,
        const unsigned short* __restrict__ Kc, const unsigned short* __restrict__ VT,
        unsigned short* __restrict__ Opart, float* __restrict__ Lpart) {
    int tid = threadIdx.x;
    int wave = tid >> 6, lane = tid & 63;
    int l31 = lane & 31, hi = lane >> 5;
    int x7 = l31 & 7;
    int b = blockIdx.y;
    int comp = blockIdx.z >> 2, split = blockIdx.z & 3;
    int q0 = blockIdx.x * 128 + wave * 32;
    int kstart = split * 1024;

    __shared__ __align__(16) unsigned short kb3[3][64 * 64];    // 8KB x3
    __shared__ __align__(16) unsigned short vb3[3][128 * 64];   // 16KB x3

    // Q B-frags: lane holds col q = q0+l31, d = j*16 + hi*8 + e
    const unsigned short* Qp = Qc + ((size_t)(comp * 2 + b) * 4096 + q0 + l31) * 64 + hi * 8;
    bf16x8 qB0 = *(const bf16x8*)(Qp);
    bf16x8 qB1 = *(const bf16x8*)(Qp + 16);
    bf16x8 qB2 = *(const bf16x8*)(Qp + 32);
    bf16x8 qB3 = *(const bf16x8*)(Qp + 48);

    f32x16 o[4];
#pragma unroll
    for (int i = 0; i < 4; ++i) o[i] = zero16();
    f32x16 ol = zero16();
    bf16x8 ones;
#pragma unroll
    for (int i = 0; i < 8; ++i) ones[i] = (short)0x3F80;

    const unsigned short* kSrc = Kc + ((size_t)(comp * 2 + b) * 4096 + kstart
                                       + wave * 8 + (lane >> 3)) * 64
                                    + ((lane & 7) ^ (lane >> 3)) * 8;
    const unsigned short* vSrc = VT + ((size_t)b * 128 + (tid >> 3)) * 4096
                                    + kstart + ((lane & 7) ^ (lane >> 3)) * 8;

    auto STAGE = [&](unsigned short* kd, unsigned short* vd, int it) {
        const unsigned short* ks = kSrc + (size_t)it * 4096;
        gl_lds16(ks,        kd + wave * 512);
        gl_lds16(ks + 2048, kd + 2048 + wave * 512);
        const unsigned short* vs = vSrc + it * 64;
#pragma unroll
        for (int ri = 0; ri < 4; ++ri)
            gl_lds16(vs + (size_t)ri * 32 * 4096, vd + ri * 2048 + wave * 512);
    };

    unsigned short *k0 = kb3[0], *k1 = kb3[1], *k2 = kb3[2];
    unsigned short *v0 = vb3[0], *v1 = vb3[1], *v2 = vb3[2];
    STAGE(k0, v0, 0);
    STAGE(k1, v1, 1);

    for (int it = 0; it < 16; ++it) {
        // wait for tile it only; tile it+1's 6 loads stay in flight across barrier
        if (it < 15) asm volatile("s_waitcnt vmcnt(6)" ::: "memory");
        else         asm volatile("s_waitcnt vmcnt(0)" ::: "memory");
        __builtin_amdgcn_sched_barrier(0);
        __builtin_amdgcn_s_barrier();
        __builtin_amdgcn_sched_barrier(0);
        if (it + 2 < 16) STAGE(k2, v2, it + 2);

        const unsigned short* kb = k0;
        const unsigned short* vb = v0;

        // S^T[k][q] for two 32-key half-tiles: A = K rows, B = Q cols
        f32x16 st0 = zero16(), st1 = zero16();
        __builtin_amdgcn_s_setprio(1);
#pragma unroll
        for (int j = 0; j < 4; ++j) {
            int ku = ((j * 2 + hi) ^ x7) * 8;
            bf16x8 kA0 = *(const bf16x8*)(kb + l31 * 64 + ku);
            bf16x8 kA1 = *(const bf16x8*)(kb + (32 + l31) * 64 + ku);
            bf16x8 qj = (j == 0) ? qB0 : (j == 1) ? qB1 : (j == 2) ? qB2 : qB3;
            st0 = MFMA32(kA0, qj, st0);
            st1 = MFMA32(kA1, qj, st1);
        }
        __builtin_amdgcn_s_setprio(0);

        // exp2 + in-register pack (v_perm truncation)
        union W4 { unsigned u[4]; bf16x8 v; };
        W4 wA0, wB0, wA1, wB1;
#pragma unroll
        for (int i2 = 0; i2 < 4; ++i2) {
            float a0 = __builtin_amdgcn_exp2f(st0[2 * i2]);
            float a1 = __builtin_amdgcn_exp2f(st0[2 * i2 + 1]);
            float a2 = __builtin_amdgcn_exp2f(st0[8 + 2 * i2]);
            float a3 = __builtin_amdgcn_exp2f(st0[9 + 2 * i2]);
            float b0 = __builtin_amdgcn_exp2f(st1[2 * i2]);
            float b1 = __builtin_amdgcn_exp2f(st1[2 * i2 + 1]);
            float b2 = __builtin_amdgcn_exp2f(st1[8 + 2 * i2]);
            float b3 = __builtin_amdgcn_exp2f(st1[9 + 2 * i2]);
            wA0.u[i2] = __builtin_amdgcn_perm(fbits(a1), fbits(a0), 0x07060302);
            wB0.u[i2] = __builtin_amdgcn_perm(fbits(a3), fbits(a2), 0x07060302);
            wA1.u[i2] = __builtin_amdgcn_perm(fbits(b1), fbits(b0), 0x07060302);
            wB1.u[i2] = __builtin_amdgcn_perm(fbits(b3), fbits(b2), 0x07060302);
        }

        // PV + row-sum: B-frag = single b128 at swizzled unit (2W+hi)^x7
        __builtin_amdgcn_s_setprio(1);
        ol = MFMA32(wA0.v, ones, ol);
        ol = MFMA32(wB0.v, ones, ol);
        ol = MFMA32(wA1.v, ones, ol);
        ol = MFMA32(wB1.v, ones, ol);
#pragma unroll
        for (int vt = 0; vt < 4; ++vt) {
            const unsigned short* vrow = vb + (vt * 32 + l31) * 64;
            o[vt] = MFMA32(wA0.v, *(const bf16x8*)(vrow + ((0 + hi) ^ x7) * 8), o[vt]);
            o[vt] = MFMA32(wB0.v, *(const bf16x8*)(vrow + ((2 + hi) ^ x7) * 8), o[vt]);
            o[vt] = MFMA32(wA1.v, *(const bf16x8*)(vrow + ((4 + hi) ^ x7) * 8), o[vt]);
            o[vt] = MFMA32(wB1.v, *(const bf16x8*)(vrow + ((6 + hi) ^ x7) * 8), o[vt]);
        }
        __builtin_amdgcn_s_setprio(0);

        // rotate buffers
        unsigned short* t;
        t = k0; k0 = k1; k1 = k2; k2 = t;
        t = v0; v0 = v1; v1 = v2; v2 = t;
    }

    int base = (b * 2 + comp) * 4 + split;
    unsigned short* op = Opart + (size_t)base * 4096 * 128;
#pragma unroll
    for (int vt = 0; vt < 4; ++vt)
#pragma unroll
        for (int r = 0; r < 16; ++r) {
            int qr = (r & 3) + 8 * (r >> 2) + 4 * hi;
            op[(size_t)(q0 + qr) * 128 + vt * 32 + l31] = f2bf(o[vt][r]);
        }
    // ol reg r = rowsum(q-row (r&3)+8*(r>>2)+4*hi), identical across cols
    if (l31 == 0) {
        float* lp = Lpart + (size_t)base * 4096 + q0;
#pragma unroll
        for (int r = 0; r < 16; ++r)
            lp[(r & 3) + 8 * (r >> 2) + 4 * hi] = ol[r];
    }
}

// ---------------- Kernel 4: out = (SUM O1s)/l1 - lam * (SUM O2s)/l2 --------------
__global__ __launch_bounds__(256) void combine(const unsigned short* __restrict__ Opart,
        const float* __restrict__ Lpart, const float* __restrict__ lamp,
        float* __restrict__ out) {
    float lam = lamp[0];
    int i = blockIdx.x * 256 + threadIdx.x;   // float4 units over 2*4096*32
    int row = i >> 5;
    int c4  = i & 31;
    int b = row >> 12, q = row & 4095;

    float l1 = 0.f, l2 = 0.f;
#pragma unroll
    for (int s = 0; s < 4; ++s) {
        l1 += Lpart[((size_t)((b * 2 + 0) * 4 + s)) * 4096 + q];
        l2 += Lpart[((size_t)((b * 2 + 1) * 4 + s)) * 4096 + q];
    }
    float rl1 = 1.0f / l1, rl2 = 1.0f / l2;

    size_t qoff = (size_t)q * 128 + c4 * 4;
    float a0 = 0.f, a1 = 0.f, a2 = 0.f, a3 = 0.f;
    float c0 = 0.f, c1 = 0.f, c2 = 0.f, c3 = 0.f;
#pragma unroll
    for (int s = 0; s < 4; ++s) {
        ushort4 p1 = *(const ushort4*)(Opart + (size_t)((b * 2 + 0) * 4 + s) * 4096 * 128 + qoff);
        ushort4 p2 = *(const ushort4*)(Opart + (size_t)((b * 2 + 1) * 4 + s) * 4096 * 128 + qoff);
        a0 += bf2f(p1.x); a1 += bf2f(p1.y); a2 += bf2f(p1.z); a3 += bf2f(p1.w);
        c0 += bf2f(p2.x); c1 += bf2f(p2.y); c2 += bf2f(p2.z); c3 += bf2f(p2.w);
    }
    float4 r;
    r.x = a0 * rl1 - lam * c0 * rl2;
    r.y = a1 * rl1 - lam * c1 * rl2;
    r.z = a2 * rl1 - lam * c2 * rl2;
    r.w = a3 * rl1 - lam * c3 * rl2;
    ((float4*)out)[i] = r;
}

extern "C" void kernel_launch(void* const* d_in, const int* in_sizes, int n_in,
                              void* d_out, int out_size, void* d_ws, size_t ws_size,
                              hipStream_t stream) {
    const float* X   = (const float*)d_in[0];
    const float* Wq  = (const float*)d_in[1];
    const float* Wk  = (const float*)d_in[2];
    const float* Wv  = (const float*)d_in[3];
    const float* lam = (const float*)d_in[4];
    float* out = (float*)d_out;

    char* ws = (char*)d_ws;
    // Layout (Opart/Lpart alias WT+Xb: proj finishes before attn writes, same stream)
    unsigned short* Qc = (unsigned short*)(ws);                    // [2][2][4096][64]  2MB
    unsigned short* Kc = (unsigned short*)(ws + 2097152);          // [2][2][4096][64]  2MB
    unsigned short* VT = (unsigned short*)(ws + 4194304);          // [2][128][4096]    2MB
    unsigned short* WT = (unsigned short*)(ws + 6291456);          // 384x1024 bf16     768KB
    unsigned short* Xb = (unsigned short*)(ws + 7077888);          // 8192x1024 bf16    16MB
    unsigned short* Opart = (unsigned short*)(ws + 6291456);       // [16][4096][128] bf16 16MB (alias)
    float* Lpart = (float*)(ws + 23068672);                        // [16][4096] f32 256KB (alias)
    // end of distinct region: 23855104 bytes

    prep_wt<<<dim3(96), dim3(256), 0, stream>>>(Wq, Wk, Wv, WT);
    prep_x<<<dim3(1024), dim3(256), 0, stream>>>(X, Xb);
    proj<<<dim3(128, 4), dim3(256), 0, stream>>>(Xb, WT, Qc, Kc, VT);
    attn<<<dim3(32, 2, 8), dim3(256), 0, stream>>>(Qc, Kc, VT, Opart, Lpart);
    combine<<<dim3(1024), dim3(256), 0, stream>>>(Opart, Lpart, lam, out);
}